// Round 1
// baseline (3291.759 us; speedup 1.0000x reference)
//
#include <hip/hip_runtime.h>
#include <math.h>

#define NN 50000
#define NE 500000
#define DD 128

#define AS_STRIDE 132   // 64-row A tile, pad 128->132 (16B-aligned rows, conflict-free reads)
#define WS_STRIDE 36    // 32-k W chunk, pad 32->36 (16B-aligned rows, 4-way worst case)

// ---------------------------------------------------------------------------
// Shared GEMM building block: C[64 rows][128 outs] += A[64][128] @ W[128 outs][128 k]^T
// Block = 256 threads. Thread t: og = t&31 -> outs {og, og+32, og+64, og+96}
//                                rg = t>>5 -> rows {rg, rg+8, ..., rg+56}
// W staged in 4 chunks of 32 k into LDS.
// ---------------------------------------------------------------------------
__device__ __forceinline__ void layer_matmul(const float* __restrict__ W,
                                             const float* As, float* Ws,
                                             float acc[4][8],
                                             int t, int og, int rg)
{
    for (int kc = 0; kc < 4; ++kc) {
        __syncthreads();   // previous users of Ws (and As writers) done
        // stage W[0:128][kc*32 : kc*32+32] -> Ws
        #pragma unroll
        for (int i = 0; i < 16; ++i) {
            int idx = i * 256 + t;      // 0..4095
            int o  = idx >> 5;
            int kk = idx & 31;
            Ws[o * WS_STRIDE + kk] = W[o * DD + kc * 32 + kk];
        }
        __syncthreads();
        #pragma unroll
        for (int kk = 0; kk < 32; kk += 4) {
            float4 wv[4];
            float4 xv[8];
            #pragma unroll
            for (int j = 0; j < 4; ++j)
                wv[j] = *reinterpret_cast<const float4*>(&Ws[(og + 32 * j) * WS_STRIDE + kk]);
            #pragma unroll
            for (int i = 0; i < 8; ++i)
                xv[i] = *reinterpret_cast<const float4*>(&As[(rg + 8 * i) * AS_STRIDE + kc * 32 + kk]);
            #pragma unroll
            for (int j = 0; j < 4; ++j) {
                #pragma unroll
                for (int i = 0; i < 8; ++i) {
                    acc[j][i] += wv[j].x * xv[i].x + wv[j].y * xv[i].y
                               + wv[j].z * xv[i].z + wv[j].w * xv[i].w;
                }
            }
        }
    }
}

__device__ __forceinline__ void zero_acc(float acc[4][8])
{
    #pragma unroll
    for (int j = 0; j < 4; ++j)
        #pragma unroll
        for (int i = 0; i < 8; ++i)
            acc[j][i] = 0.f;
}

// ---------------------------------------------------------------------------
// Kernel 1: fused encoders.  h1 = x@Wk^T+bk ; p1 = x@Wp1^T+bp1 ; p2 = x@Wp2^T+bp2
// Reads x tile once per block.
// ---------------------------------------------------------------------------
__global__ __launch_bounds__(256) void enc_kernel(
    const float* __restrict__ x,
    const float* __restrict__ Wk,  const float* __restrict__ bk,
    const float* __restrict__ Wp1, const float* __restrict__ bp1,
    const float* __restrict__ Wp2, const float* __restrict__ bp2,
    float* __restrict__ h1, float* __restrict__ p1, float* __restrict__ p2)
{
    __shared__ alignas(16) float As[64 * AS_STRIDE];
    __shared__ alignas(16) float Ws[128 * WS_STRIDE];
    const int t  = threadIdx.x;
    const int og = t & 31;
    const int rg = t >> 5;
    const int row0 = blockIdx.x * 64;

    #pragma unroll 4
    for (int i = 0; i < 32; ++i) {
        int idx = i * 256 + t;
        int r = idx >> 7, c = idx & 127;
        int gr = row0 + r;
        As[r * AS_STRIDE + c] = (gr < NN) ? x[gr * DD + c] : 0.f;
    }

    float acc[4][8];

    // --- encoder K ---
    zero_acc(acc);
    layer_matmul(Wk, As, Ws, acc, t, og, rg);
    #pragma unroll
    for (int j = 0; j < 4; ++j) {
        float bv = bk[og + 32 * j];
        #pragma unroll
        for (int i = 0; i < 8; ++i) {
            int gr = row0 + rg + 8 * i;
            if (gr < NN) h1[gr * DD + og + 32 * j] = acc[j][i] + bv;
        }
    }
    // --- encoder P1 ---
    zero_acc(acc);
    layer_matmul(Wp1, As, Ws, acc, t, og, rg);
    #pragma unroll
    for (int j = 0; j < 4; ++j) {
        float bv = bp1[og + 32 * j];
        #pragma unroll
        for (int i = 0; i < 8; ++i) {
            int gr = row0 + rg + 8 * i;
            if (gr < NN) p1[gr * DD + og + 32 * j] = acc[j][i] + bv;
        }
    }
    // --- encoder P2 ---
    zero_acc(acc);
    layer_matmul(Wp2, As, Ws, acc, t, og, rg);
    #pragma unroll
    for (int j = 0; j < 4; ++j) {
        float bv = bp2[og + 32 * j];
        #pragma unroll
        for (int i = 0; i < 8; ++i) {
            int gr = row0 + rg + 8 * i;
            if (gr < NN) p2[gr * DD + og + 32 * j] = acc[j][i] + bv;
        }
    }
}

// ---------------------------------------------------------------------------
// Kernel 2: hagg[dst[e]] += h1[src[e]]  (atomic scatter-add, 64M f32 atomics)
// ---------------------------------------------------------------------------
__global__ __launch_bounds__(256) void scatter_kernel(
    const float* __restrict__ h1,
    const int* __restrict__ src, const int* __restrict__ dst,
    float* __restrict__ hagg)
{
    int gid = blockIdx.x * 256 + threadIdx.x;
    if (gid < NE * DD) {
        int e = gid >> 7;
        int c = gid & 127;
        atomicAdd(&hagg[dst[e] * DD + c], h1[src[e] * DD + c]);
    }
}

// ---------------------------------------------------------------------------
// Kernel 3: node MLP.  Kn = W2@relu(W1@tanh(W0@hagg + b0) + b1) + b2  (row-wise)
// Activations kept in-place in the LDS A tile.
// ---------------------------------------------------------------------------
__global__ __launch_bounds__(256) void node_mlp_kernel(
    const float* __restrict__ hin,
    const float* __restrict__ W0, const float* __restrict__ b0,
    const float* __restrict__ W1, const float* __restrict__ b1,
    const float* __restrict__ W2, const float* __restrict__ b2,
    float* __restrict__ out)
{
    __shared__ alignas(16) float As[64 * AS_STRIDE];
    __shared__ alignas(16) float Ws[128 * WS_STRIDE];
    const int t  = threadIdx.x;
    const int og = t & 31;
    const int rg = t >> 5;
    const int row0 = blockIdx.x * 64;

    #pragma unroll 4
    for (int i = 0; i < 32; ++i) {
        int idx = i * 256 + t;
        int r = idx >> 7, c = idx & 127;
        int gr = row0 + r;
        As[r * AS_STRIDE + c] = (gr < NN) ? hin[gr * DD + c] : 0.f;
    }

    float acc[4][8];

    // layer 0: tanh
    zero_acc(acc);
    layer_matmul(W0, As, Ws, acc, t, og, rg);
    __syncthreads();  // all reads of As done before overwrite
    #pragma unroll
    for (int j = 0; j < 4; ++j) {
        float bv = b0[og + 32 * j];
        #pragma unroll
        for (int i = 0; i < 8; ++i)
            As[(rg + 8 * i) * AS_STRIDE + og + 32 * j] = tanhf(acc[j][i] + bv);
    }

    // layer 1: relu
    zero_acc(acc);
    layer_matmul(W1, As, Ws, acc, t, og, rg);
    __syncthreads();
    #pragma unroll
    for (int j = 0; j < 4; ++j) {
        float bv = b1[og + 32 * j];
        #pragma unroll
        for (int i = 0; i < 8; ++i)
            As[(rg + 8 * i) * AS_STRIDE + og + 32 * j] = fmaxf(acc[j][i] + bv, 0.f);
    }

    // layer 2: linear -> global
    zero_acc(acc);
    layer_matmul(W2, As, Ws, acc, t, og, rg);
    #pragma unroll
    for (int j = 0; j < 4; ++j) {
        float bv = b2[og + 32 * j];
        #pragma unroll
        for (int i = 0; i < 8; ++i) {
            int gr = row0 + rg + 8 * i;
            if (gr < NN) out[gr * DD + og + 32 * j] = acc[j][i] + bv;
        }
    }
}

// ---------------------------------------------------------------------------
// Kernel 4: edge MLP fused with final dot-reduction.
// u = p1[src]+p2[dst]; e = U2@relu(U1@tanh(U0@u+b0)+b1)+b2;
// out += dot(Kn[src], e)   (block-reduced, one atomic per block)
// ---------------------------------------------------------------------------
__global__ __launch_bounds__(256) void edge_mlp_kernel(
    const float* __restrict__ p1, const float* __restrict__ p2,
    const float* __restrict__ Kn,
    const int* __restrict__ src, const int* __restrict__ dst,
    const float* __restrict__ W0, const float* __restrict__ b0,
    const float* __restrict__ W1, const float* __restrict__ b1,
    const float* __restrict__ W2, const float* __restrict__ b2,
    float* __restrict__ out)
{
    __shared__ alignas(16) float As[64 * AS_STRIDE];
    __shared__ alignas(16) float Ws[128 * WS_STRIDE];
    __shared__ int sidx[64];
    __shared__ int didx[64];
    __shared__ float red[4];
    const int t  = threadIdx.x;
    const int og = t & 31;
    const int rg = t >> 5;
    const int e0 = blockIdx.x * 64;

    if (t < 64) {
        int e = e0 + t;
        sidx[t] = (e < NE) ? src[e] : -1;
        didx[t] = (e < NE) ? dst[e] : 0;
    }
    __syncthreads();

    #pragma unroll 4
    for (int i = 0; i < 32; ++i) {
        int idx = i * 256 + t;
        int r = idx >> 7, c = idx & 127;
        int s = sidx[r];
        As[r * AS_STRIDE + c] = (s >= 0) ? p1[s * DD + c] + p2[didx[r] * DD + c] : 0.f;
    }

    float acc[4][8];

    // layer 0: tanh
    zero_acc(acc);
    layer_matmul(W0, As, Ws, acc, t, og, rg);
    __syncthreads();
    #pragma unroll
    for (int j = 0; j < 4; ++j) {
        float bv = b0[og + 32 * j];
        #pragma unroll
        for (int i = 0; i < 8; ++i)
            As[(rg + 8 * i) * AS_STRIDE + og + 32 * j] = tanhf(acc[j][i] + bv);
    }

    // layer 1: relu
    zero_acc(acc);
    layer_matmul(W1, As, Ws, acc, t, og, rg);
    __syncthreads();
    #pragma unroll
    for (int j = 0; j < 4; ++j) {
        float bv = b1[og + 32 * j];
        #pragma unroll
        for (int i = 0; i < 8; ++i)
            As[(rg + 8 * i) * AS_STRIDE + og + 32 * j] = fmaxf(acc[j][i] + bv, 0.f);
    }

    // layer 2: linear, fused dot with Kn[src]
    zero_acc(acc);
    layer_matmul(W2, As, Ws, acc, t, og, rg);

    float part = 0.f;
    #pragma unroll
    for (int j = 0; j < 4; ++j) {
        float bv = b2[og + 32 * j];
        #pragma unroll
        for (int i = 0; i < 8; ++i) {
            int s = sidx[rg + 8 * i];
            if (s >= 0)
                part += (acc[j][i] + bv) * Kn[s * DD + og + 32 * j];
        }
    }
    // wave (64-lane) reduction, then cross-wave via LDS, one atomic per block
    #pragma unroll
    for (int off = 32; off > 0; off >>= 1)
        part += __shfl_down(part, off);
    if ((t & 63) == 0) red[t >> 6] = part;
    __syncthreads();
    if (t == 0)
        atomicAdd(out, red[0] + red[1] + red[2] + red[3]);
}

// ---------------------------------------------------------------------------
extern "C" void kernel_launch(void* const* d_in, const int* in_sizes, int n_in,
                              void* d_out, int out_size, void* d_ws, size_t ws_size,
                              hipStream_t stream)
{
    const float* x     = (const float*)d_in[0];
    const int*   src   = (const int*)  d_in[1];
    const int*   dst   = (const int*)  d_in[2];
    const float* WencK = (const float*)d_in[3];
    const float* bencK = (const float*)d_in[4];
    const float* WencP1= (const float*)d_in[5];
    const float* bencP1= (const float*)d_in[6];
    const float* WencP2= (const float*)d_in[7];
    const float* bencP2= (const float*)d_in[8];
    const float* K0W   = (const float*)d_in[9];
    const float* K0b   = (const float*)d_in[10];
    const float* K1W   = (const float*)d_in[11];
    const float* K1b   = (const float*)d_in[12];
    const float* K2W   = (const float*)d_in[13];
    const float* K2b   = (const float*)d_in[14];
    const float* U0W   = (const float*)d_in[15];
    const float* U0b   = (const float*)d_in[16];
    const float* U1W   = (const float*)d_in[17];
    const float* U1b   = (const float*)d_in[18];
    const float* U2W   = (const float*)d_in[19];
    const float* U2b   = (const float*)d_in[20];

    float* ws   = (float*)d_ws;
    float* h1   = ws;                       // [N,D], reused later as Knode
    float* hagg = ws + (size_t)NN * DD;     // [N,D]
    float* p1   = ws + (size_t)2 * NN * DD; // [N,D]
    float* p2   = ws + (size_t)3 * NN * DD; // [N,D]
    float* Kn   = h1;                       // h1 dead after scatter

    hipMemsetAsync(hagg, 0, (size_t)NN * DD * sizeof(float), stream);
    hipMemsetAsync(d_out, 0, sizeof(float), stream);

    enc_kernel<<<(NN + 63) / 64, 256, 0, stream>>>(
        x, WencK, bencK, WencP1, bencP1, WencP2, bencP2, h1, p1, p2);

    scatter_kernel<<<(NE * DD + 255) / 256, 256, 0, stream>>>(h1, src, dst, hagg);

    node_mlp_kernel<<<(NN + 63) / 64, 256, 0, stream>>>(
        hagg, K0W, K0b, K1W, K1b, K2W, K2b, Kn);

    edge_mlp_kernel<<<(NE + 63) / 64, 256, 0, stream>>>(
        p1, p2, Kn, src, dst, U0W, U0b, U1W, U1b, U2W, U2b, (float*)d_out);
}

// Round 2
// 1160.583 us; speedup vs baseline: 2.8363x; 2.8363x over previous
//
#include <hip/hip_runtime.h>
#include <math.h>

#define NN 50000
#define NE 500000
#define DD 128
#define STR 136   // LDS activation row stride in bf16 elements (136*2B=272B=68 words; 68%32=4 -> bank-even frag reads)

typedef __attribute__((ext_vector_type(8))) short short8;
typedef __attribute__((ext_vector_type(4))) float floatx4;

__device__ __forceinline__ float bf2f(unsigned short u) {
    unsigned v = ((unsigned)u) << 16;
    float f;
    __builtin_memcpy(&f, &v, 4);
    return f;
}
__device__ __forceinline__ unsigned short f2bf(float f) {
    unsigned x;
    __builtin_memcpy(&x, &f, 4);
    x += 0x7FFF + ((x >> 16) & 1);   // RNE
    return (unsigned short)(x >> 16);
}

// ---------------------------------------------------------------------------
// Weight preconversion: f32 [n][k] row-major -> bf16 B-fragment order
//   out[((kt*8 + nt)*64 + lane)*8 + j] = W[nt*16 + (lane&15)][ k_src ]
//   k_src = k_stored for identity layers; = inv_pi(k_stored) for pi-permuted
//   layers (their input activations were stored with cols at pi(n)).
// pi(n) = 4*(n&15) + ((n>>4)&3) + (n&64); inv: a=(k&63)>>2, b=k&3, f=(k&64)+16b+a
// ---------------------------------------------------------------------------
__global__ __launch_bounds__(256) void preconv_kernel(
    const float* __restrict__ W0, const float* __restrict__ W1,
    const float* __restrict__ W2, const float* __restrict__ W3,
    const float* __restrict__ W4, const float* __restrict__ W5,
    const float* __restrict__ W6, const float* __restrict__ W7,
    const float* __restrict__ W8, unsigned short* __restrict__ out)
{
    int g = blockIdx.x * 256 + threadIdx.x;
    if (g >= 9 * 2048) return;
    int m   = g >> 11;
    int rem = g & 2047;
    int kt = rem >> 9, nt = (rem >> 6) & 7, lane = rem & 63;
    const float* W;
    switch (m) {
        case 0: W = W0; break; case 1: W = W1; break; case 2: W = W2; break;
        case 3: W = W3; break; case 4: W = W4; break; case 5: W = W5; break;
        case 6: W = W6; break; case 7: W = W7; break; default: W = W8; break;
    }
    bool perm = (m == 4 || m == 5 || m == 7 || m == 8);
    int n = nt * 16 + (lane & 15);
    #pragma unroll
    for (int j = 0; j < 8; ++j) {
        int ks = kt * 32 + (lane >> 4) * 8 + j;
        int f = ks;
        if (perm) f = (ks & 64) + 16 * (ks & 3) + ((ks & 63) >> 2);
        out[(size_t)g * 8 + j] = f2bf(W[n * DD + f]);
    }
}

// ---------------------------------------------------------------------------
// Kernel 1: fused encoders via MFMA. h1 (f32, natural), p1/p2 (bf16, natural)
// Block = 128 rows x 128 outs, 4 waves in 2x2 (wm, wn), each 64x64.
// ---------------------------------------------------------------------------
__global__ __launch_bounds__(256) void enc_kernel(
    const float* __restrict__ x, const unsigned short* __restrict__ wf,
    const float* __restrict__ bk, const float* __restrict__ bp1,
    const float* __restrict__ bp2,
    float* __restrict__ h1, unsigned short* __restrict__ p1,
    unsigned short* __restrict__ p2)
{
    __shared__ unsigned short A[128 * STR];
    const int t = threadIdx.x;
    const int lane = t & 63, w = t >> 6;
    const int wm = w >> 1, wn = w & 1;
    const int c = lane & 15, q = lane >> 4;
    const int row0 = blockIdx.x * 128;

    #pragma unroll
    for (int i = 0; i < 16; ++i) {
        int idx = i * 256 + t;
        int r = idx >> 5, ch = idx & 31;
        int gr = row0 + r;
        ushort4 v4 = {0, 0, 0, 0};
        if (gr < NN) {
            float4 f = *(const float4*)&x[(size_t)gr * DD + ch * 4];
            v4.x = f2bf(f.x); v4.y = f2bf(f.y); v4.z = f2bf(f.z); v4.w = f2bf(f.w);
        }
        *(ushort4*)&A[r * STR + ch * 4] = v4;
    }
    __syncthreads();

    for (int l = 0; l < 3; ++l) {
        floatx4 acc[4][4];
        #pragma unroll
        for (int i = 0; i < 4; ++i)
            #pragma unroll
            for (int j = 0; j < 4; ++j)
                acc[i][j] = (floatx4){0.f, 0.f, 0.f, 0.f};
        const short8* W8 = (const short8*)(wf + (size_t)l * 16384);
        #pragma unroll
        for (int kt = 0; kt < 4; ++kt) {
            short8 af[4], bfr[4];
            #pragma unroll
            for (int i = 0; i < 4; ++i)
                af[i] = *(const short8*)&A[(wm * 64 + i * 16 + c) * STR + kt * 32 + q * 8];
            #pragma unroll
            for (int j = 0; j < 4; ++j)
                bfr[j] = W8[(kt * 8 + wn * 4 + j) * 64 + lane];
            #pragma unroll
            for (int i = 0; i < 4; ++i)
                #pragma unroll
                for (int j = 0; j < 4; ++j)
                    acc[i][j] = __builtin_amdgcn_mfma_f32_16x16x32_bf16(af[i], bfr[j], acc[i][j], 0, 0, 0);
        }
        const float* bb = (l == 0) ? bk : (l == 1) ? bp1 : bp2;
        float bv[4];
        #pragma unroll
        for (int j = 0; j < 4; ++j) bv[j] = bb[c + 16 * j + 64 * wn];

        if (l == 0) {
            #pragma unroll
            for (int i = 0; i < 4; ++i)
                #pragma unroll
                for (int r = 0; r < 4; ++r) {
                    int node = row0 + wm * 64 + i * 16 + 4 * q + r;
                    if (node < NN) {
                        #pragma unroll
                        for (int j = 0; j < 4; ++j)
                            h1[(size_t)node * DD + c + 16 * j + 64 * wn] = acc[i][j][r] + bv[j];
                    }
                }
        } else {
            unsigned short* pp = (l == 1) ? p1 : p2;
            #pragma unroll
            for (int i = 0; i < 4; ++i)
                #pragma unroll
                for (int r = 0; r < 4; ++r) {
                    int node = row0 + wm * 64 + i * 16 + 4 * q + r;
                    if (node < NN) {
                        #pragma unroll
                        for (int j = 0; j < 4; ++j)
                            pp[(size_t)node * DD + c + 16 * j + 64 * wn] = f2bf(acc[i][j][r] + bv[j]);
                    }
                }
        }
    }
}

// ---------------------------------------------------------------------------
// Kernel 2: hagg[dst[e]] += h1[src[e]]  (f32 atomics, 4 cols/thread)
// ---------------------------------------------------------------------------
__global__ __launch_bounds__(256) void scatter_kernel(
    const float* __restrict__ h1,
    const int* __restrict__ src, const int* __restrict__ dst,
    float* __restrict__ hagg)
{
    int gid = blockIdx.x * 256 + threadIdx.x;
    if (gid < NE * 32) {
        int e = gid >> 5, ch = gid & 31;
        float4 v = *(const float4*)&h1[(size_t)src[e] * DD + ch * 4];
        float* d = &hagg[(size_t)dst[e] * DD + ch * 4];
        atomicAdd(d + 0, v.x); atomicAdd(d + 1, v.y);
        atomicAdd(d + 2, v.z); atomicAdd(d + 3, v.w);
    }
}

// ---------------------------------------------------------------------------
// Kernel 3: node MLP via MFMA. Input hagg f32, output Kn bf16 pi-permuted.
// Inter-layer activations in LDS (bf16, pi-packed ds_write_b64 epilogues).
// ---------------------------------------------------------------------------
__global__ __launch_bounds__(256) void node_mlp_kernel(
    const float* __restrict__ hin, const unsigned short* __restrict__ wf,
    const float* __restrict__ b0, const float* __restrict__ b1,
    const float* __restrict__ b2, unsigned short* __restrict__ Kn)
{
    __shared__ unsigned short A[128 * STR];
    const int t = threadIdx.x;
    const int lane = t & 63, w = t >> 6;
    const int wm = w >> 1, wn = w & 1;
    const int c = lane & 15, q = lane >> 4;
    const int row0 = blockIdx.x * 128;

    #pragma unroll
    for (int i = 0; i < 16; ++i) {
        int idx = i * 256 + t;
        int r = idx >> 5, ch = idx & 31;
        int gr = row0 + r;
        ushort4 v4 = {0, 0, 0, 0};
        if (gr < NN) {
            float4 f = *(const float4*)&hin[(size_t)gr * DD + ch * 4];
            v4.x = f2bf(f.x); v4.y = f2bf(f.y); v4.z = f2bf(f.z); v4.w = f2bf(f.w);
        }
        *(ushort4*)&A[r * STR + ch * 4] = v4;
    }
    __syncthreads();

    for (int l = 0; l < 3; ++l) {
        floatx4 acc[4][4];
        #pragma unroll
        for (int i = 0; i < 4; ++i)
            #pragma unroll
            for (int j = 0; j < 4; ++j)
                acc[i][j] = (floatx4){0.f, 0.f, 0.f, 0.f};
        const short8* W8 = (const short8*)(wf + (size_t)(3 + l) * 16384);
        #pragma unroll
        for (int kt = 0; kt < 4; ++kt) {
            short8 af[4], bfr[4];
            #pragma unroll
            for (int i = 0; i < 4; ++i)
                af[i] = *(const short8*)&A[(wm * 64 + i * 16 + c) * STR + kt * 32 + q * 8];
            #pragma unroll
            for (int j = 0; j < 4; ++j)
                bfr[j] = W8[(kt * 8 + wn * 4 + j) * 64 + lane];
            #pragma unroll
            for (int i = 0; i < 4; ++i)
                #pragma unroll
                for (int j = 0; j < 4; ++j)
                    acc[i][j] = __builtin_amdgcn_mfma_f32_16x16x32_bf16(af[i], bfr[j], acc[i][j], 0, 0, 0);
        }
        const float* bb = (l == 0) ? b0 : (l == 1) ? b1 : b2;
        float bv[4];
        #pragma unroll
        for (int j = 0; j < 4; ++j) bv[j] = bb[c + 16 * j + 64 * wn];

        if (l < 2) {
            __syncthreads();
            #pragma unroll
            for (int i = 0; i < 4; ++i)
                #pragma unroll
                for (int r = 0; r < 4; ++r) {
                    ushort4 pk;
                    float v0 = acc[i][0][r] + bv[0], v1 = acc[i][1][r] + bv[1];
                    float v2 = acc[i][2][r] + bv[2], v3 = acc[i][3][r] + bv[3];
                    if (l == 0) {
                        v0 = tanhf(v0); v1 = tanhf(v1); v2 = tanhf(v2); v3 = tanhf(v3);
                    } else {
                        v0 = fmaxf(v0, 0.f); v1 = fmaxf(v1, 0.f);
                        v2 = fmaxf(v2, 0.f); v3 = fmaxf(v3, 0.f);
                    }
                    pk.x = f2bf(v0); pk.y = f2bf(v1); pk.z = f2bf(v2); pk.w = f2bf(v3);
                    int m = wm * 64 + i * 16 + 4 * q + r;
                    *(ushort4*)&A[m * STR + 4 * c + 64 * wn] = pk;   // pi-packed
                }
            __syncthreads();
        } else {
            // store Kn bf16 pi-permuted: col n -> 4*(n&15) + ((n>>4)&3) + (n&64)
            #pragma unroll
            for (int i = 0; i < 4; ++i)
                #pragma unroll
                for (int r = 0; r < 4; ++r) {
                    int node = row0 + wm * 64 + i * 16 + 4 * q + r;
                    if (node < NN) {
                        ushort4 pk;
                        pk.x = f2bf(acc[i][0][r] + bv[0]);
                        pk.y = f2bf(acc[i][1][r] + bv[1]);
                        pk.z = f2bf(acc[i][2][r] + bv[2]);
                        pk.w = f2bf(acc[i][3][r] + bv[3]);
                        *(ushort4*)&Kn[(size_t)node * DD + 4 * c + 64 * wn] = pk;
                    }
                }
        }
    }
}

// ---------------------------------------------------------------------------
// Kernel 4: edge MLP via MFMA, fused with dot(Kn[src], .) scalar reduction.
// ---------------------------------------------------------------------------
__global__ __launch_bounds__(256) void edge_mlp_kernel(
    const unsigned short* __restrict__ p1, const unsigned short* __restrict__ p2,
    const unsigned short* __restrict__ Kn,
    const int* __restrict__ src, const int* __restrict__ dst,
    const unsigned short* __restrict__ wf,
    const float* __restrict__ b0, const float* __restrict__ b1,
    const float* __restrict__ b2, float* __restrict__ out)
{
    __shared__ unsigned short A[128 * STR];
    __shared__ int sidx[128];
    __shared__ int didx[128];
    __shared__ float red[4];
    const int t = threadIdx.x;
    const int lane = t & 63, w = t >> 6;
    const int wm = w >> 1, wn = w & 1;
    const int c = lane & 15, q = lane >> 4;
    const int e0 = blockIdx.x * 128;

    if (t < 128) {
        int e = e0 + t;
        sidx[t] = (e < NE) ? src[e] : -1;
        didx[t] = (e < NE) ? dst[e] : 0;
    }
    __syncthreads();

    // stage u = p1[s] + p2[d] (bf16 add in f32), natural col order
    #pragma unroll
    for (int i = 0; i < 8; ++i) {
        int idx = i * 256 + t;
        int r = idx >> 4, ch = idx & 15;
        int s = sidx[r];
        short8 o8 = (short8){0,0,0,0,0,0,0,0};
        if (s >= 0) {
            short8 a8 = *(const short8*)&p1[(size_t)s * DD + ch * 8];
            short8 b8 = *(const short8*)&p2[(size_t)didx[r] * DD + ch * 8];
            #pragma unroll
            for (int k = 0; k < 8; ++k)
                o8[k] = (short)f2bf(bf2f((unsigned short)a8[k]) + bf2f((unsigned short)b8[k]));
        }
        *(short8*)&A[r * STR + ch * 8] = o8;
    }
    __syncthreads();

    float part = 0.f;

    for (int l = 0; l < 3; ++l) {
        floatx4 acc[4][4];
        #pragma unroll
        for (int i = 0; i < 4; ++i)
            #pragma unroll
            for (int j = 0; j < 4; ++j)
                acc[i][j] = (floatx4){0.f, 0.f, 0.f, 0.f};
        const short8* W8 = (const short8*)(wf + (size_t)(6 + l) * 16384);
        #pragma unroll
        for (int kt = 0; kt < 4; ++kt) {
            short8 af[4], bfr[4];
            #pragma unroll
            for (int i = 0; i < 4; ++i)
                af[i] = *(const short8*)&A[(wm * 64 + i * 16 + c) * STR + kt * 32 + q * 8];
            #pragma unroll
            for (int j = 0; j < 4; ++j)
                bfr[j] = W8[(kt * 8 + wn * 4 + j) * 64 + lane];
            #pragma unroll
            for (int i = 0; i < 4; ++i)
                #pragma unroll
                for (int j = 0; j < 4; ++j)
                    acc[i][j] = __builtin_amdgcn_mfma_f32_16x16x32_bf16(af[i], bfr[j], acc[i][j], 0, 0, 0);
        }
        const float* bb = (l == 0) ? b0 : (l == 1) ? b1 : b2;
        float bv[4];
        #pragma unroll
        for (int j = 0; j < 4; ++j) bv[j] = bb[c + 16 * j + 64 * wn];

        if (l < 2) {
            __syncthreads();
            #pragma unroll
            for (int i = 0; i < 4; ++i)
                #pragma unroll
                for (int r = 0; r < 4; ++r) {
                    float v0 = acc[i][0][r] + bv[0], v1 = acc[i][1][r] + bv[1];
                    float v2 = acc[i][2][r] + bv[2], v3 = acc[i][3][r] + bv[3];
                    if (l == 0) {
                        v0 = tanhf(v0); v1 = tanhf(v1); v2 = tanhf(v2); v3 = tanhf(v3);
                    } else {
                        v0 = fmaxf(v0, 0.f); v1 = fmaxf(v1, 0.f);
                        v2 = fmaxf(v2, 0.f); v3 = fmaxf(v3, 0.f);
                    }
                    ushort4 pk;
                    pk.x = f2bf(v0); pk.y = f2bf(v1); pk.z = f2bf(v2); pk.w = f2bf(v3);
                    int m = wm * 64 + i * 16 + 4 * q + r;
                    *(ushort4*)&A[m * STR + 4 * c + 64 * wn] = pk;   // pi-packed
                }
            __syncthreads();
        } else {
            // fused dot with Kn[src] (pi-permuted bf16 -> contiguous 8B gather)
            #pragma unroll
            for (int i = 0; i < 4; ++i)
                #pragma unroll
                for (int r = 0; r < 4; ++r) {
                    int m = wm * 64 + i * 16 + 4 * q + r;
                    int s = sidx[m];
                    if (s >= 0) {
                        ushort4 kn = *(const ushort4*)&Kn[(size_t)s * DD + 4 * c + 64 * wn];
                        part += (acc[i][0][r] + bv[0]) * bf2f(kn.x)
                              + (acc[i][1][r] + bv[1]) * bf2f(kn.y)
                              + (acc[i][2][r] + bv[2]) * bf2f(kn.z)
                              + (acc[i][3][r] + bv[3]) * bf2f(kn.w);
                    }
                }
        }
    }

    #pragma unroll
    for (int off = 32; off > 0; off >>= 1)
        part += __shfl_down(part, off);
    if (lane == 0) red[w] = part;
    __syncthreads();
    if (t == 0)
        atomicAdd(out, red[0] + red[1] + red[2] + red[3]);
}

// ---------------------------------------------------------------------------
extern "C" void kernel_launch(void* const* d_in, const int* in_sizes, int n_in,
                              void* d_out, int out_size, void* d_ws, size_t ws_size,
                              hipStream_t stream)
{
    const float* x     = (const float*)d_in[0];
    const int*   src   = (const int*)  d_in[1];
    const int*   dst   = (const int*)  d_in[2];
    const float* WencK = (const float*)d_in[3];
    const float* bencK = (const float*)d_in[4];
    const float* WencP1= (const float*)d_in[5];
    const float* bencP1= (const float*)d_in[6];
    const float* WencP2= (const float*)d_in[7];
    const float* bencP2= (const float*)d_in[8];
    const float* K0W   = (const float*)d_in[9];
    const float* K0b   = (const float*)d_in[10];
    const float* K1W   = (const float*)d_in[11];
    const float* K1b   = (const float*)d_in[12];
    const float* K2W   = (const float*)d_in[13];
    const float* K2b   = (const float*)d_in[14];
    const float* U0W   = (const float*)d_in[15];
    const float* U0b   = (const float*)d_in[16];
    const float* U1W   = (const float*)d_in[17];
    const float* U1b   = (const float*)d_in[18];
    const float* U2W   = (const float*)d_in[19];
    const float* U2b   = (const float*)d_in[20];

    float* ws = (float*)d_ws;
    unsigned short* wfrag = (unsigned short*)ws;          // 9*16384 bf16 = 294912 B
    float* h1   = ws + 80000;                             // [N,D] f32
    float* hagg = h1 + (size_t)NN * DD;                   // [N,D] f32
    unsigned short* p1 = (unsigned short*)(hagg + (size_t)NN * DD);
    unsigned short* p2 = p1 + (size_t)NN * DD;
    unsigned short* Kn = p2 + (size_t)NN * DD;

    hipMemsetAsync(hagg, 0, (size_t)NN * DD * sizeof(float), stream);
    hipMemsetAsync(d_out, 0, sizeof(float), stream);

    preconv_kernel<<<(9 * 2048 + 255) / 256, 256, 0, stream>>>(
        WencK, WencP1, WencP2, K0W, K1W, K2W, U0W, U1W, U2W, wfrag);

    enc_kernel<<<(NN + 127) / 128, 256, 0, stream>>>(
        x, wfrag, bencK, bencP1, bencP2, h1, p1, p2);

    scatter_kernel<<<(NE * 32 + 255) / 256, 256, 0, stream>>>(h1, src, dst, hagg);

    node_mlp_kernel<<<(NN + 127) / 128, 256, 0, stream>>>(
        hagg, wfrag, K0b, K1b, K2b, Kn);

    edge_mlp_kernel<<<(NE + 127) / 128, 256, 0, stream>>>(
        p1, p2, Kn, src, dst, wfrag, U0b, U1b, U2b, (float*)d_out);
}

// Round 3
// 480.895 us; speedup vs baseline: 6.8451x; 2.4134x over previous
//
#include <hip/hip_runtime.h>
#include <math.h>

#define NN 50000
#define NE 500000
#define DD 128
#define STR 136   // LDS activation row stride in bf16 elements

typedef __attribute__((ext_vector_type(8))) short short8;
typedef __attribute__((ext_vector_type(4))) float floatx4;

__device__ __forceinline__ float bf2f(unsigned short u) {
    unsigned v = ((unsigned)u) << 16;
    float f;
    __builtin_memcpy(&f, &v, 4);
    return f;
}
__device__ __forceinline__ unsigned short f2bf(float f) {
    unsigned x;
    __builtin_memcpy(&x, &f, 4);
    x += 0x7FFF + ((x >> 16) & 1);   // RNE
    return (unsigned short)(x >> 16);
}

// ---------------------------------------------------------------------------
// Weight preconversion: f32 [n][k] row-major -> bf16 B-fragment order
//   out[((kt*8 + nt)*64 + lane)*8 + j] = W[nt*16 + (lane&15)][ k_src ]
// pi(n) = 4*(n&15) + ((n>>4)&3) + (n&64); inv: a=(k&63)>>2, b=k&3, f=(k&64)+16b+a
// ---------------------------------------------------------------------------
__global__ __launch_bounds__(256) void preconv_kernel(
    const float* __restrict__ W0, const float* __restrict__ W1,
    const float* __restrict__ W2, const float* __restrict__ W3,
    const float* __restrict__ W4, const float* __restrict__ W5,
    const float* __restrict__ W6, const float* __restrict__ W7,
    const float* __restrict__ W8, unsigned short* __restrict__ out)
{
    int g = blockIdx.x * 256 + threadIdx.x;
    if (g >= 9 * 2048) return;
    int m   = g >> 11;
    int rem = g & 2047;
    int kt = rem >> 9, nt = (rem >> 6) & 7, lane = rem & 63;
    const float* W;
    switch (m) {
        case 0: W = W0; break; case 1: W = W1; break; case 2: W = W2; break;
        case 3: W = W3; break; case 4: W = W4; break; case 5: W = W5; break;
        case 6: W = W6; break; case 7: W = W7; break; default: W = W8; break;
    }
    bool perm = (m == 4 || m == 5 || m == 7 || m == 8);
    int n = nt * 16 + (lane & 15);
    #pragma unroll
    for (int j = 0; j < 8; ++j) {
        int ks = kt * 32 + (lane >> 4) * 8 + j;
        int f = ks;
        if (perm) f = (ks & 64) + 16 * (ks & 3) + ((ks & 63) >> 2);
        out[(size_t)g * 8 + j] = f2bf(W[n * DD + f]);
    }
}

// ---------------------------------------------------------------------------
// Kernel 1: fused encoders via MFMA. h1/p1/p2 all bf16, natural col order.
// ---------------------------------------------------------------------------
__global__ __launch_bounds__(256) void enc_kernel(
    const float* __restrict__ x, const unsigned short* __restrict__ wf,
    const float* __restrict__ bk, const float* __restrict__ bp1,
    const float* __restrict__ bp2,
    unsigned short* __restrict__ h1, unsigned short* __restrict__ p1,
    unsigned short* __restrict__ p2)
{
    __shared__ unsigned short A[128 * STR];
    const int t = threadIdx.x;
    const int lane = t & 63, w = t >> 6;
    const int wm = w >> 1, wn = w & 1;
    const int c = lane & 15, q = lane >> 4;
    const int row0 = blockIdx.x * 128;

    #pragma unroll
    for (int i = 0; i < 16; ++i) {
        int idx = i * 256 + t;
        int r = idx >> 5, ch = idx & 31;
        int gr = row0 + r;
        ushort4 v4 = {0, 0, 0, 0};
        if (gr < NN) {
            float4 f = *(const float4*)&x[(size_t)gr * DD + ch * 4];
            v4.x = f2bf(f.x); v4.y = f2bf(f.y); v4.z = f2bf(f.z); v4.w = f2bf(f.w);
        }
        *(ushort4*)&A[r * STR + ch * 4] = v4;
    }
    __syncthreads();

    for (int l = 0; l < 3; ++l) {
        floatx4 acc[4][4];
        #pragma unroll
        for (int i = 0; i < 4; ++i)
            #pragma unroll
            for (int j = 0; j < 4; ++j)
                acc[i][j] = (floatx4){0.f, 0.f, 0.f, 0.f};
        const short8* W8 = (const short8*)(wf + (size_t)l * 16384);
        #pragma unroll
        for (int kt = 0; kt < 4; ++kt) {
            short8 af[4], bfr[4];
            #pragma unroll
            for (int i = 0; i < 4; ++i)
                af[i] = *(const short8*)&A[(wm * 64 + i * 16 + c) * STR + kt * 32 + q * 8];
            #pragma unroll
            for (int j = 0; j < 4; ++j)
                bfr[j] = W8[(kt * 8 + wn * 4 + j) * 64 + lane];
            #pragma unroll
            for (int i = 0; i < 4; ++i)
                #pragma unroll
                for (int j = 0; j < 4; ++j)
                    acc[i][j] = __builtin_amdgcn_mfma_f32_16x16x32_bf16(af[i], bfr[j], acc[i][j], 0, 0, 0);
        }
        const float* bb = (l == 0) ? bk : (l == 1) ? bp1 : bp2;
        unsigned short* pp = (l == 0) ? h1 : (l == 1) ? p1 : p2;
        float bv[4];
        #pragma unroll
        for (int j = 0; j < 4; ++j) bv[j] = bb[c + 16 * j + 64 * wn];

        #pragma unroll
        for (int i = 0; i < 4; ++i)
            #pragma unroll
            for (int r = 0; r < 4; ++r) {
                int node = row0 + wm * 64 + i * 16 + 4 * q + r;
                if (node < NN) {
                    #pragma unroll
                    for (int j = 0; j < 4; ++j)
                        pp[(size_t)node * DD + c + 16 * j + 64 * wn] = f2bf(acc[i][j][r] + bv[j]);
                }
            }
    }
}

// ---------------------------------------------------------------------------
// Segment-sum via counting sort (no float atomics).
// ---------------------------------------------------------------------------
__global__ __launch_bounds__(256) void hist_kernel(
    const int* __restrict__ dst, int* __restrict__ cnt)
{
    int e = blockIdx.x * 256 + threadIdx.x;
    if (e < NE) atomicAdd(&cnt[dst[e]], 1);
}

__global__ __launch_bounds__(1024) void scan_kernel(
    const int* __restrict__ cnt, int* __restrict__ base)
{
    const int CH = 49;   // 1024*49 = 50176 >= NN
    __shared__ int partial[1024];
    int t = threadIdx.x;
    int start = t * CH;
    int s = 0;
    for (int i = 0; i < CH; ++i) {
        int idx = start + i;
        if (idx < NN) s += cnt[idx];
    }
    partial[t] = s;
    __syncthreads();
    for (int off = 1; off < 1024; off <<= 1) {
        int v = (t >= off) ? partial[t - off] : 0;
        __syncthreads();
        partial[t] += v;
        __syncthreads();
    }
    int excl = (t == 0) ? 0 : partial[t - 1];
    for (int i = 0; i < CH; ++i) {
        int idx = start + i;
        if (idx < NN) {
            base[idx] = excl;
            excl += cnt[idx];
        }
    }
}

__global__ __launch_bounds__(256) void place_kernel(
    const int* __restrict__ src, const int* __restrict__ dst,
    const int* __restrict__ base, int* __restrict__ cursor,
    int* __restrict__ sorted_src)
{
    int e = blockIdx.x * 256 + threadIdx.x;
    if (e < NE) {
        int d = dst[e];
        int pos = base[d] + atomicAdd(&cursor[d], 1);
        sorted_src[pos] = src[e];
    }
}

// One wave per node: lanes hold 2 cols each; broadcast src ids via shfl.
__global__ __launch_bounds__(256) void agg_kernel(
    const unsigned short* __restrict__ h1,
    const int* __restrict__ base, const int* __restrict__ cnt,
    const int* __restrict__ sorted_src,
    unsigned short* __restrict__ hagg)
{
    int wave = blockIdx.x * 4 + (threadIdx.x >> 6);
    int lane = threadIdx.x & 63;
    if (wave >= NN) return;
    int lo = base[wave];
    int hi = lo + cnt[wave];
    float ax = 0.f, ay = 0.f;
    for (int off = lo; off < hi; off += 64) {
        int myid = (off + lane < hi) ? sorted_src[off + lane] : 0;
        int nk = min(64, hi - off);
        for (int k = 0; k < nk; ++k) {
            int s = __shfl(myid, k);
            ushort2 v = *(const ushort2*)&h1[(size_t)s * DD + lane * 2];
            ax += bf2f(v.x);
            ay += bf2f(v.y);
        }
    }
    ushort2 o;
    o.x = f2bf(ax); o.y = f2bf(ay);
    *(ushort2*)&hagg[(size_t)wave * DD + lane * 2] = o;
}

// ---------------------------------------------------------------------------
// Kernel 3: node MLP via MFMA. Input hagg bf16, output Kn bf16 pi-permuted.
// ---------------------------------------------------------------------------
__global__ __launch_bounds__(256) void node_mlp_kernel(
    const unsigned short* __restrict__ hin, const unsigned short* __restrict__ wf,
    const float* __restrict__ b0, const float* __restrict__ b1,
    const float* __restrict__ b2, unsigned short* __restrict__ Kn)
{
    __shared__ unsigned short A[128 * STR];
    const int t = threadIdx.x;
    const int lane = t & 63, w = t >> 6;
    const int wm = w >> 1, wn = w & 1;
    const int c = lane & 15, q = lane >> 4;
    const int row0 = blockIdx.x * 128;

    #pragma unroll
    for (int i = 0; i < 8; ++i) {
        int idx = i * 256 + t;
        int r = idx >> 4, ch = idx & 15;
        int gr = row0 + r;
        short8 v = (short8){0,0,0,0,0,0,0,0};
        if (gr < NN) v = *(const short8*)&hin[(size_t)gr * DD + ch * 8];
        *(short8*)&A[r * STR + ch * 8] = v;
    }
    __syncthreads();

    for (int l = 0; l < 3; ++l) {
        floatx4 acc[4][4];
        #pragma unroll
        for (int i = 0; i < 4; ++i)
            #pragma unroll
            for (int j = 0; j < 4; ++j)
                acc[i][j] = (floatx4){0.f, 0.f, 0.f, 0.f};
        const short8* W8 = (const short8*)(wf + (size_t)(3 + l) * 16384);
        #pragma unroll
        for (int kt = 0; kt < 4; ++kt) {
            short8 af[4], bfr[4];
            #pragma unroll
            for (int i = 0; i < 4; ++i)
                af[i] = *(const short8*)&A[(wm * 64 + i * 16 + c) * STR + kt * 32 + q * 8];
            #pragma unroll
            for (int j = 0; j < 4; ++j)
                bfr[j] = W8[(kt * 8 + wn * 4 + j) * 64 + lane];
            #pragma unroll
            for (int i = 0; i < 4; ++i)
                #pragma unroll
                for (int j = 0; j < 4; ++j)
                    acc[i][j] = __builtin_amdgcn_mfma_f32_16x16x32_bf16(af[i], bfr[j], acc[i][j], 0, 0, 0);
        }
        const float* bb = (l == 0) ? b0 : (l == 1) ? b1 : b2;
        float bv[4];
        #pragma unroll
        for (int j = 0; j < 4; ++j) bv[j] = bb[c + 16 * j + 64 * wn];

        if (l < 2) {
            __syncthreads();
            #pragma unroll
            for (int i = 0; i < 4; ++i)
                #pragma unroll
                for (int r = 0; r < 4; ++r) {
                    ushort4 pk;
                    float v0 = acc[i][0][r] + bv[0], v1 = acc[i][1][r] + bv[1];
                    float v2 = acc[i][2][r] + bv[2], v3 = acc[i][3][r] + bv[3];
                    if (l == 0) {
                        v0 = tanhf(v0); v1 = tanhf(v1); v2 = tanhf(v2); v3 = tanhf(v3);
                    } else {
                        v0 = fmaxf(v0, 0.f); v1 = fmaxf(v1, 0.f);
                        v2 = fmaxf(v2, 0.f); v3 = fmaxf(v3, 0.f);
                    }
                    pk.x = f2bf(v0); pk.y = f2bf(v1); pk.z = f2bf(v2); pk.w = f2bf(v3);
                    int m = wm * 64 + i * 16 + 4 * q + r;
                    *(ushort4*)&A[m * STR + 4 * c + 64 * wn] = pk;   // pi-packed
                }
            __syncthreads();
        } else {
            #pragma unroll
            for (int i = 0; i < 4; ++i)
                #pragma unroll
                for (int r = 0; r < 4; ++r) {
                    int node = row0 + wm * 64 + i * 16 + 4 * q + r;
                    if (node < NN) {
                        ushort4 pk;
                        pk.x = f2bf(acc[i][0][r] + bv[0]);
                        pk.y = f2bf(acc[i][1][r] + bv[1]);
                        pk.z = f2bf(acc[i][2][r] + bv[2]);
                        pk.w = f2bf(acc[i][3][r] + bv[3]);
                        *(ushort4*)&Kn[(size_t)node * DD + 4 * c + 64 * wn] = pk;
                    }
                }
        }
    }
}

// ---------------------------------------------------------------------------
// Kernel 4: edge MLP via MFMA, fused with dot(Kn[src], .) scalar reduction.
// ---------------------------------------------------------------------------
__global__ __launch_bounds__(256) void edge_mlp_kernel(
    const unsigned short* __restrict__ p1, const unsigned short* __restrict__ p2,
    const unsigned short* __restrict__ Kn,
    const int* __restrict__ src, const int* __restrict__ dst,
    const unsigned short* __restrict__ wf,
    const float* __restrict__ b0, const float* __restrict__ b1,
    const float* __restrict__ b2, float* __restrict__ out)
{
    __shared__ unsigned short A[128 * STR];
    __shared__ int sidx[128];
    __shared__ int didx[128];
    __shared__ float red[4];
    const int t = threadIdx.x;
    const int lane = t & 63, w = t >> 6;
    const int wm = w >> 1, wn = w & 1;
    const int c = lane & 15, q = lane >> 4;
    const int e0 = blockIdx.x * 128;

    if (t < 128) {
        int e = e0 + t;
        sidx[t] = (e < NE) ? src[e] : -1;
        didx[t] = (e < NE) ? dst[e] : 0;
    }
    __syncthreads();

    #pragma unroll
    for (int i = 0; i < 8; ++i) {
        int idx = i * 256 + t;
        int r = idx >> 4, ch = idx & 15;
        int s = sidx[r];
        short8 o8 = (short8){0,0,0,0,0,0,0,0};
        if (s >= 0) {
            short8 a8 = *(const short8*)&p1[(size_t)s * DD + ch * 8];
            short8 b8 = *(const short8*)&p2[(size_t)didx[r] * DD + ch * 8];
            #pragma unroll
            for (int k = 0; k < 8; ++k)
                o8[k] = (short)f2bf(bf2f((unsigned short)a8[k]) + bf2f((unsigned short)b8[k]));
        }
        *(short8*)&A[r * STR + ch * 8] = o8;
    }
    __syncthreads();

    float part = 0.f;

    for (int l = 0; l < 3; ++l) {
        floatx4 acc[4][4];
        #pragma unroll
        for (int i = 0; i < 4; ++i)
            #pragma unroll
            for (int j = 0; j < 4; ++j)
                acc[i][j] = (floatx4){0.f, 0.f, 0.f, 0.f};
        const short8* W8 = (const short8*)(wf + (size_t)(6 + l) * 16384);
        #pragma unroll
        for (int kt = 0; kt < 4; ++kt) {
            short8 af[4], bfr[4];
            #pragma unroll
            for (int i = 0; i < 4; ++i)
                af[i] = *(const short8*)&A[(wm * 64 + i * 16 + c) * STR + kt * 32 + q * 8];
            #pragma unroll
            for (int j = 0; j < 4; ++j)
                bfr[j] = W8[(kt * 8 + wn * 4 + j) * 64 + lane];
            #pragma unroll
            for (int i = 0; i < 4; ++i)
                #pragma unroll
                for (int j = 0; j < 4; ++j)
                    acc[i][j] = __builtin_amdgcn_mfma_f32_16x16x32_bf16(af[i], bfr[j], acc[i][j], 0, 0, 0);
        }
        const float* bb = (l == 0) ? b0 : (l == 1) ? b1 : b2;
        float bv[4];
        #pragma unroll
        for (int j = 0; j < 4; ++j) bv[j] = bb[c + 16 * j + 64 * wn];

        if (l < 2) {
            __syncthreads();
            #pragma unroll
            for (int i = 0; i < 4; ++i)
                #pragma unroll
                for (int r = 0; r < 4; ++r) {
                    float v0 = acc[i][0][r] + bv[0], v1 = acc[i][1][r] + bv[1];
                    float v2 = acc[i][2][r] + bv[2], v3 = acc[i][3][r] + bv[3];
                    if (l == 0) {
                        v0 = tanhf(v0); v1 = tanhf(v1); v2 = tanhf(v2); v3 = tanhf(v3);
                    } else {
                        v0 = fmaxf(v0, 0.f); v1 = fmaxf(v1, 0.f);
                        v2 = fmaxf(v2, 0.f); v3 = fmaxf(v3, 0.f);
                    }
                    ushort4 pk;
                    pk.x = f2bf(v0); pk.y = f2bf(v1); pk.z = f2bf(v2); pk.w = f2bf(v3);
                    int m = wm * 64 + i * 16 + 4 * q + r;
                    *(ushort4*)&A[m * STR + 4 * c + 64 * wn] = pk;   // pi-packed
                }
            __syncthreads();
        } else {
            #pragma unroll
            for (int i = 0; i < 4; ++i)
                #pragma unroll
                for (int r = 0; r < 4; ++r) {
                    int m = wm * 64 + i * 16 + 4 * q + r;
                    int s = sidx[m];
                    if (s >= 0) {
                        ushort4 kn = *(const ushort4*)&Kn[(size_t)s * DD + 4 * c + 64 * wn];
                        part += (acc[i][0][r] + bv[0]) * bf2f(kn.x)
                              + (acc[i][1][r] + bv[1]) * bf2f(kn.y)
                              + (acc[i][2][r] + bv[2]) * bf2f(kn.z)
                              + (acc[i][3][r] + bv[3]) * bf2f(kn.w);
                    }
                }
        }
    }

    #pragma unroll
    for (int off = 32; off > 0; off >>= 1)
        part += __shfl_down(part, off);
    if (lane == 0) red[w] = part;
    __syncthreads();
    if (t == 0)
        atomicAdd(out, red[0] + red[1] + red[2] + red[3]);
}

// ---------------------------------------------------------------------------
extern "C" void kernel_launch(void* const* d_in, const int* in_sizes, int n_in,
                              void* d_out, int out_size, void* d_ws, size_t ws_size,
                              hipStream_t stream)
{
    const float* x     = (const float*)d_in[0];
    const int*   src   = (const int*)  d_in[1];
    const int*   dst   = (const int*)  d_in[2];
    const float* WencK = (const float*)d_in[3];
    const float* bencK = (const float*)d_in[4];
    const float* WencP1= (const float*)d_in[5];
    const float* bencP1= (const float*)d_in[6];
    const float* WencP2= (const float*)d_in[7];
    const float* bencP2= (const float*)d_in[8];
    const float* K0W   = (const float*)d_in[9];
    const float* K0b   = (const float*)d_in[10];
    const float* K1W   = (const float*)d_in[11];
    const float* K1b   = (const float*)d_in[12];
    const float* K2W   = (const float*)d_in[13];
    const float* K2b   = (const float*)d_in[14];
    const float* U0W   = (const float*)d_in[15];
    const float* U0b   = (const float*)d_in[16];
    const float* U1W   = (const float*)d_in[17];
    const float* U1b   = (const float*)d_in[18];
    const float* U2W   = (const float*)d_in[19];
    const float* U2b   = (const float*)d_in[20];

    char* ws = (char*)d_ws;
    unsigned short* wfrag = (unsigned short*)ws;             // 294912 B
    unsigned short* h1   = (unsigned short*)(ws + 0x60000);  // [N,D] bf16 12.8MB
    unsigned short* p1   = h1 + (size_t)NN * DD;
    unsigned short* p2   = p1 + (size_t)NN * DD;
    unsigned short* Kn   = p2 + (size_t)NN * DD;
    unsigned short* hagg = Kn + (size_t)NN * DD;
    int* cnt        = (int*)(hagg + (size_t)NN * DD);
    int* base       = cnt + NN;
    int* cursor     = base + NN;
    int* sorted_src = cursor + NN;

    hipMemsetAsync(cnt, 0, NN * sizeof(int), stream);
    hipMemsetAsync(cursor, 0, NN * sizeof(int), stream);
    hipMemsetAsync(d_out, 0, sizeof(float), stream);

    preconv_kernel<<<(9 * 2048 + 255) / 256, 256, 0, stream>>>(
        WencK, WencP1, WencP2, K0W, K1W, K2W, U0W, U1W, U2W, wfrag);

    hist_kernel<<<(NE + 255) / 256, 256, 0, stream>>>(dst, cnt);
    scan_kernel<<<1, 1024, 0, stream>>>(cnt, base);
    place_kernel<<<(NE + 255) / 256, 256, 0, stream>>>(src, dst, base, cursor, sorted_src);

    enc_kernel<<<(NN + 127) / 128, 256, 0, stream>>>(
        x, wfrag, bencK, bencP1, bencP2, h1, p1, p2);

    agg_kernel<<<(NN + 3) / 4, 256, 0, stream>>>(h1, base, cnt, sorted_src, hagg);

    node_mlp_kernel<<<(NN + 127) / 128, 256, 0, stream>>>(
        hagg, wfrag, K0b, K1b, K2b, Kn);

    edge_mlp_kernel<<<(NE + 127) / 128, 256, 0, stream>>>(
        p1, p2, Kn, src, dst, wfrag, U0b, U1b, U2b, (float*)d_out);
}

// Round 4
// 443.785 us; speedup vs baseline: 7.4175x; 1.0836x over previous
//
#include <hip/hip_runtime.h>
#include <math.h>

#define NN 50000
#define NE 500000
#define DD 128
#define STR 136   // LDS activation row stride in bf16 elements

typedef __attribute__((ext_vector_type(8))) short short8;
typedef __attribute__((ext_vector_type(4))) float floatx4;

__device__ __forceinline__ float bf2f(unsigned short u) {
    unsigned v = ((unsigned)u) << 16;
    float f;
    __builtin_memcpy(&f, &v, 4);
    return f;
}
__device__ __forceinline__ unsigned short f2bf(float f) {
    unsigned x;
    __builtin_memcpy(&x, &f, 4);
    x += 0x7FFF + ((x >> 16) & 1);   // RNE
    return (unsigned short)(x >> 16);
}
// tanh(x) = 1 - 2/(e^{2x}+1), e^{2x} = exp2(2*log2e*x). Branch-free, ~5 VALU ops.
__device__ __forceinline__ float fast_tanh(float x) {
    float t = __builtin_amdgcn_exp2f(x * 2.88539008177793f);
    return 1.f - 2.f * __builtin_amdgcn_rcpf(t + 1.f);
}

// ---------------------------------------------------------------------------
// Composite weights (f32): blocks 0-5 compute
//   comp0 = U0W@WencP1, comp1 = U0W@WencP2, comp2 = K0W@WencK  (64 rows/block)
// block 6: bias vectors: bq = U0W@(bp1+bp2)+U0b ; bvec = K0W@bencK ;
//          u2bp[ks] = U2b[invpi(ks)]
// ---------------------------------------------------------------------------
__global__ __launch_bounds__(256) void composite_kernel(
    const float* __restrict__ U0W, const float* __restrict__ WencP1,
    const float* __restrict__ WencP2, const float* __restrict__ K0W,
    const float* __restrict__ WencK,
    const float* __restrict__ bp1, const float* __restrict__ bp2,
    const float* __restrict__ U0b, const float* __restrict__ bk,
    const float* __restrict__ U2b,
    float* __restrict__ comp, float* __restrict__ bvecs)
{
    int b = blockIdx.x;
    int t = threadIdx.x;
    if (b == 6) {
        if (t < 128) {
            float s1 = 0.f, s2 = 0.f;
            for (int k = 0; k < DD; ++k) {
                s1 += U0W[t * DD + k] * (bp1[k] + bp2[k]);
                s2 += K0W[t * DD + k] * bk[k];
            }
            bvecs[t] = s1 + U0b[t];
            bvecs[128 + t] = s2;
            int f = (t & 64) + 16 * (t & 3) + ((t & 63) >> 2);
            bvecs[256 + t] = U2b[f];
        }
        return;
    }
    __shared__ float Bs[DD * DD];
    int mat = b >> 1, half = b & 1;
    const float* A = (mat == 2) ? K0W : U0W;
    const float* B = (mat == 0) ? WencP1 : (mat == 1) ? WencP2 : WencK;
    float* C = comp + (size_t)mat * DD * DD;
    for (int i = 0; i < 64; ++i)
        Bs[i * 256 + t] = B[i * 256 + t];
    __syncthreads();
    int row = half * 64 + (t >> 2);
    int j0 = (t & 3) * 32;
    float acc[32];
    #pragma unroll
    for (int jj = 0; jj < 32; ++jj) acc[jj] = 0.f;
    for (int k = 0; k < DD; ++k) {
        float a = A[row * DD + k];
        #pragma unroll
        for (int jj = 0; jj < 32; ++jj)
            acc[jj] += a * Bs[k * DD + j0 + jj];
    }
    #pragma unroll
    for (int jj = 0; jj < 32; ++jj) C[row * DD + j0 + jj] = acc[jj];
}

// ---------------------------------------------------------------------------
// Weight frag conversion. Frags: 0=Wq1(nat) 1=Wq2(nat) 2=WkK0(nat)
// 3=K1W(perm) 4=K2W(perm) 5=U2W(perm+transpose) 6=U1W(nat)
// ---------------------------------------------------------------------------
__global__ __launch_bounds__(256) void preconv_kernel(
    const float* __restrict__ comp, const float* __restrict__ K1W,
    const float* __restrict__ K2W, const float* __restrict__ U2W,
    const float* __restrict__ U1W, unsigned short* __restrict__ out)
{
    int g = blockIdx.x * 256 + threadIdx.x;
    if (g >= 7 * 2048) return;
    int m = g >> 11;
    int rem = g & 2047;
    int kt = rem >> 9, nt = (rem >> 6) & 7, lane = rem & 63;
    const float* W;
    bool perm = false, tr = false;
    switch (m) {
        case 0: W = comp; break;
        case 1: W = comp + 16384; break;
        case 2: W = comp + 32768; break;
        case 3: W = K1W; perm = true; break;
        case 4: W = K2W; perm = true; break;
        case 5: W = U2W; perm = true; tr = true; break;
        default: W = U1W; break;
    }
    int n = nt * 16 + (lane & 15);
    #pragma unroll
    for (int j = 0; j < 8; ++j) {
        int ks = kt * 32 + (lane >> 4) * 8 + j;
        int f = perm ? (ks & 64) + 16 * (ks & 3) + ((ks & 63) >> 2) : ks;
        float v = tr ? W[f * DD + n] : W[n * DD + f];
        out[(size_t)g * 8 + j] = f2bf(v);
    }
}

// ---------------------------------------------------------------------------
// Counting sort of edges by dst.
// ---------------------------------------------------------------------------
__global__ __launch_bounds__(256) void hist_kernel(
    const int* __restrict__ dst, int* __restrict__ cnt)
{
    int e = blockIdx.x * 256 + threadIdx.x;
    if (e < NE) atomicAdd(&cnt[dst[e]], 1);
}

__global__ __launch_bounds__(1024) void scan_kernel(
    const int* __restrict__ cnt, int* __restrict__ base)
{
    const int CH = 49;
    __shared__ int partial[1024];
    int t = threadIdx.x;
    int start = t * CH;
    int s = 0;
    for (int i = 0; i < CH; ++i) {
        int idx = start + i;
        if (idx < NN) s += cnt[idx];
    }
    partial[t] = s;
    __syncthreads();
    for (int off = 1; off < 1024; off <<= 1) {
        int v = (t >= off) ? partial[t - off] : 0;
        __syncthreads();
        partial[t] += v;
        __syncthreads();
    }
    int excl = (t == 0) ? 0 : partial[t - 1];
    for (int i = 0; i < CH; ++i) {
        int idx = start + i;
        if (idx < NN) {
            base[idx] = excl;
            excl += cnt[idx];
        }
    }
}

__global__ __launch_bounds__(256) void place_kernel(
    const int* __restrict__ src, const int* __restrict__ dst,
    const int* __restrict__ base, int* __restrict__ cursor,
    int* __restrict__ sorted_src)
{
    int e = blockIdx.x * 256 + threadIdx.x;
    if (e < NE) {
        int d = dst[e];
        int pos = base[d] + atomicAdd(&cursor[d], 1);
        sorted_src[pos] = src[e];
    }
}

// ---------------------------------------------------------------------------
// Kernel: enc. q1 = x@Wq1^T + bq ; q2 = x@Wq2^T. Also emits xbf (bf16 copy of x).
// ---------------------------------------------------------------------------
__global__ __launch_bounds__(256) void enc_kernel(
    const float* __restrict__ x, const unsigned short* __restrict__ wf,
    const float* __restrict__ bvecs,
    unsigned short* __restrict__ q1, unsigned short* __restrict__ q2,
    unsigned short* __restrict__ xbf)
{
    __shared__ unsigned short A[128 * STR];
    const int t = threadIdx.x;
    const int lane = t & 63, w = t >> 6;
    const int wm = w >> 1, wn = w & 1;
    const int c = lane & 15, q = lane >> 4;
    const int row0 = blockIdx.x * 128;

    #pragma unroll
    for (int i = 0; i < 16; ++i) {
        int idx = i * 256 + t;
        int r = idx >> 5, ch = idx & 31;
        int gr = row0 + r;
        ushort4 v4 = {0, 0, 0, 0};
        if (gr < NN) {
            float4 f = *(const float4*)&x[(size_t)gr * DD + ch * 4];
            v4.x = f2bf(f.x); v4.y = f2bf(f.y); v4.z = f2bf(f.z); v4.w = f2bf(f.w);
            *(ushort4*)&xbf[(size_t)gr * DD + ch * 4] = v4;
        }
        *(ushort4*)&A[r * STR + ch * 4] = v4;
    }
    __syncthreads();

    for (int l = 0; l < 2; ++l) {
        floatx4 acc[4][4];
        #pragma unroll
        for (int i = 0; i < 4; ++i)
            #pragma unroll
            for (int j = 0; j < 4; ++j)
                acc[i][j] = (floatx4){0.f, 0.f, 0.f, 0.f};
        const short8* W8 = (const short8*)(wf + (size_t)l * 16384);
        #pragma unroll
        for (int kt = 0; kt < 4; ++kt) {
            short8 af[4], bfr[4];
            #pragma unroll
            for (int i = 0; i < 4; ++i)
                af[i] = *(const short8*)&A[(wm * 64 + i * 16 + c) * STR + kt * 32 + q * 8];
            #pragma unroll
            for (int j = 0; j < 4; ++j)
                bfr[j] = W8[(kt * 8 + wn * 4 + j) * 64 + lane];
            #pragma unroll
            for (int i = 0; i < 4; ++i)
                #pragma unroll
                for (int j = 0; j < 4; ++j)
                    acc[i][j] = __builtin_amdgcn_mfma_f32_16x16x32_bf16(af[i], bfr[j], acc[i][j], 0, 0, 0);
        }
        unsigned short* pp = (l == 0) ? q1 : q2;
        float bv[4];
        #pragma unroll
        for (int j = 0; j < 4; ++j)
            bv[j] = (l == 0) ? bvecs[c + 16 * j + 64 * wn] : 0.f;

        #pragma unroll
        for (int i = 0; i < 4; ++i)
            #pragma unroll
            for (int r = 0; r < 4; ++r) {
                int node = row0 + wm * 64 + i * 16 + 4 * q + r;
                if (node < NN) {
                    #pragma unroll
                    for (int j = 0; j < 4; ++j)
                        pp[(size_t)node * DD + c + 16 * j + 64 * wn] = f2bf(acc[i][j][r] + bv[j]);
                }
            }
    }
}

// ---------------------------------------------------------------------------
// Kernel: agg. xagg[n] = sum over sorted src rows of xbf. One wave per node.
// ---------------------------------------------------------------------------
__global__ __launch_bounds__(256) void agg_kernel(
    const unsigned short* __restrict__ xbf,
    const int* __restrict__ base, const int* __restrict__ cnt,
    const int* __restrict__ sorted_src,
    unsigned short* __restrict__ xagg)
{
    int wave = blockIdx.x * 4 + (threadIdx.x >> 6);
    int lane = threadIdx.x & 63;
    if (wave >= NN) return;
    int lo = base[wave];
    int hi = lo + cnt[wave];
    float ax = 0.f, ay = 0.f;
    for (int off = lo; off < hi; off += 64) {
        int myid = (off + lane < hi) ? sorted_src[off + lane] : 0;
        int nk = min(64, hi - off);
        for (int k = 0; k < nk; ++k) {
            int s = __shfl(myid, k);
            ushort2 v = *(const ushort2*)&xbf[(size_t)s * DD + lane * 2];
            ax += bf2f(v.x);
            ay += bf2f(v.y);
        }
    }
    ushort2 o;
    o.x = f2bf(ax); o.y = f2bf(ay);
    *(ushort2*)&xagg[(size_t)wave * DD + lane * 2] = o;
}

// ---------------------------------------------------------------------------
// Kernel: node. 4 chained GEMMs on xagg:
//  L0: WkK0, bias K0b + cnt*bvec, tanh      -> LDS (pi-packed)
//  L1: K1W (perm), bias K1b, relu           -> LDS (pi-packed)
//  L2: K2W (perm), bias K2b                 -> Kn in LDS (pi-packed) ; kb = Kn.U2b
//  L3: U2^T (perm)                          -> Km global (pi-permuted bf16)
// ---------------------------------------------------------------------------
__global__ __launch_bounds__(256) void node_kernel(
    const unsigned short* __restrict__ xagg, const unsigned short* __restrict__ wf,
    const int* __restrict__ cnt, const float* __restrict__ bvecs,
    const float* __restrict__ K0b, const float* __restrict__ K1b,
    const float* __restrict__ K2b,
    unsigned short* __restrict__ Km, float* __restrict__ kb)
{
    __shared__ unsigned short A[128 * STR];
    const int t = threadIdx.x;
    const int lane = t & 63, w = t >> 6;
    const int wm = w >> 1, wn = w & 1;
    const int c = lane & 15, q = lane >> 4;
    const int row0 = blockIdx.x * 128;

    #pragma unroll
    for (int i = 0; i < 8; ++i) {
        int idx = i * 256 + t;
        int r = idx >> 4, ch = idx & 15;
        int gr = row0 + r;
        short8 v = (short8){0,0,0,0,0,0,0,0};
        if (gr < NN) v = *(const short8*)&xagg[(size_t)gr * DD + ch * 8];
        *(short8*)&A[r * STR + ch * 8] = v;
    }
    __syncthreads();

    for (int l = 0; l < 4; ++l) {
        floatx4 acc[4][4];
        #pragma unroll
        for (int i = 0; i < 4; ++i)
            #pragma unroll
            for (int j = 0; j < 4; ++j)
                acc[i][j] = (floatx4){0.f, 0.f, 0.f, 0.f};
        const short8* W8 = (const short8*)(wf + (size_t)(2 + l) * 16384);
        #pragma unroll
        for (int kt = 0; kt < 4; ++kt) {
            short8 af[4], bfr[4];
            #pragma unroll
            for (int i = 0; i < 4; ++i)
                af[i] = *(const short8*)&A[(wm * 64 + i * 16 + c) * STR + kt * 32 + q * 8];
            #pragma unroll
            for (int j = 0; j < 4; ++j)
                bfr[j] = W8[(kt * 8 + wn * 4 + j) * 64 + lane];
            #pragma unroll
            for (int i = 0; i < 4; ++i)
                #pragma unroll
                for (int j = 0; j < 4; ++j)
                    acc[i][j] = __builtin_amdgcn_mfma_f32_16x16x32_bf16(af[i], bfr[j], acc[i][j], 0, 0, 0);
        }

        if (l < 3) {
            const float* bb = (l == 0) ? K0b : (l == 1) ? K1b : K2b;
            float bv[4];
            #pragma unroll
            for (int j = 0; j < 4; ++j) bv[j] = bb[c + 16 * j + 64 * wn];
            float bvv[4];
            #pragma unroll
            for (int j = 0; j < 4; ++j)
                bvv[j] = (l == 0) ? bvecs[128 + c + 16 * j + 64 * wn] : 0.f;

            __syncthreads();
            #pragma unroll
            for (int i = 0; i < 4; ++i)
                #pragma unroll
                for (int r = 0; r < 4; ++r) {
                    int node = row0 + wm * 64 + i * 16 + 4 * q + r;
                    float cn = (l == 0) ? (float)((node < NN) ? cnt[node] : 0) : 0.f;
                    float v0 = acc[i][0][r] + bv[0] + cn * bvv[0];
                    float v1 = acc[i][1][r] + bv[1] + cn * bvv[1];
                    float v2 = acc[i][2][r] + bv[2] + cn * bvv[2];
                    float v3 = acc[i][3][r] + bv[3] + cn * bvv[3];
                    if (l == 0) {
                        v0 = fast_tanh(v0); v1 = fast_tanh(v1);
                        v2 = fast_tanh(v2); v3 = fast_tanh(v3);
                    } else if (l == 1) {
                        v0 = fmaxf(v0, 0.f); v1 = fmaxf(v1, 0.f);
                        v2 = fmaxf(v2, 0.f); v3 = fmaxf(v3, 0.f);
                    }
                    ushort4 pk;
                    pk.x = f2bf(v0); pk.y = f2bf(v1); pk.z = f2bf(v2); pk.w = f2bf(v3);
                    int m = wm * 64 + i * 16 + 4 * q + r;
                    *(ushort4*)&A[m * STR + 4 * c + 64 * wn] = pk;   // pi-packed
                }
            __syncthreads();

            if (l == 2) {
                // kb[n] = Kn[n] . U2b  (Kn pi-packed in LDS; bvecs[256+] pre-permuted)
                if (t < 128) {
                    int node = row0 + t;
                    if (node < NN) {
                        float s = 0.f;
                        #pragma unroll
                        for (int ch = 0; ch < 16; ++ch) {
                            short8 v = *(const short8*)&A[t * STR + ch * 8];
                            #pragma unroll
                            for (int e = 0; e < 8; ++e)
                                s += bf2f((unsigned short)v[e]) * bvecs[256 + ch * 8 + e];
                        }
                        kb[node] = s;
                    }
                }
            }
        } else {
            #pragma unroll
            for (int i = 0; i < 4; ++i)
                #pragma unroll
                for (int r = 0; r < 4; ++r) {
                    int node = row0 + wm * 64 + i * 16 + 4 * q + r;
                    if (node < NN) {
                        ushort4 pk;
                        pk.x = f2bf(acc[i][0][r]);
                        pk.y = f2bf(acc[i][1][r]);
                        pk.z = f2bf(acc[i][2][r]);
                        pk.w = f2bf(acc[i][3][r]);
                        *(ushort4*)&Km[(size_t)node * DD + 4 * c + 64 * wn] = pk;
                    }
                }
        }
    }
}

// ---------------------------------------------------------------------------
// Kernel: edge. u = tanh(q1[s]+q2[d]); a = relu(u@U1^T + U1b);
// out += a.Km[s] + kb[s]
// ---------------------------------------------------------------------------
__global__ __launch_bounds__(256) void edge_kernel(
    const unsigned short* __restrict__ q1, const unsigned short* __restrict__ q2,
    const unsigned short* __restrict__ Km, const float* __restrict__ kb,
    const int* __restrict__ src, const int* __restrict__ dst,
    const unsigned short* __restrict__ wf, const float* __restrict__ U1b,
    float* __restrict__ out)
{
    __shared__ unsigned short A[128 * STR];
    __shared__ int sidx[128];
    __shared__ int didx[128];
    __shared__ float red[4];
    const int t = threadIdx.x;
    const int lane = t & 63, w = t >> 6;
    const int wm = w >> 1, wn = w & 1;
    const int c = lane & 15, q = lane >> 4;
    const int e0 = blockIdx.x * 128;

    if (t < 128) {
        int e = e0 + t;
        sidx[t] = (e < NE) ? src[e] : -1;
        didx[t] = (e < NE) ? dst[e] : 0;
    }
    __syncthreads();

    float part = 0.f;
    if (t < 128 && sidx[t] >= 0) part += kb[sidx[t]];

    #pragma unroll
    for (int i = 0; i < 8; ++i) {
        int idx = i * 256 + t;
        int r = idx >> 4, ch = idx & 15;
        int s = sidx[r];
        short8 o8 = (short8){0,0,0,0,0,0,0,0};
        if (s >= 0) {
            short8 a8 = *(const short8*)&q1[(size_t)s * DD + ch * 8];
            short8 b8 = *(const short8*)&q2[(size_t)didx[r] * DD + ch * 8];
            #pragma unroll
            for (int k = 0; k < 8; ++k)
                o8[k] = (short)f2bf(fast_tanh(bf2f((unsigned short)a8[k]) + bf2f((unsigned short)b8[k])));
        }
        *(short8*)&A[r * STR + ch * 8] = o8;
    }
    __syncthreads();

    floatx4 acc[4][4];
    #pragma unroll
    for (int i = 0; i < 4; ++i)
        #pragma unroll
        for (int j = 0; j < 4; ++j)
            acc[i][j] = (floatx4){0.f, 0.f, 0.f, 0.f};
    const short8* W8 = (const short8*)(wf + (size_t)6 * 16384);
    #pragma unroll
    for (int kt = 0; kt < 4; ++kt) {
        short8 af[4], bfr[4];
        #pragma unroll
        for (int i = 0; i < 4; ++i)
            af[i] = *(const short8*)&A[(wm * 64 + i * 16 + c) * STR + kt * 32 + q * 8];
        #pragma unroll
        for (int j = 0; j < 4; ++j)
            bfr[j] = W8[(kt * 8 + wn * 4 + j) * 64 + lane];
        #pragma unroll
        for (int i = 0; i < 4; ++i)
            #pragma unroll
            for (int j = 0; j < 4; ++j)
                acc[i][j] = __builtin_amdgcn_mfma_f32_16x16x32_bf16(af[i], bfr[j], acc[i][j], 0, 0, 0);
    }
    float bv[4];
    #pragma unroll
    for (int j = 0; j < 4; ++j) bv[j] = U1b[c + 16 * j + 64 * wn];

    #pragma unroll
    for (int i = 0; i < 4; ++i)
        #pragma unroll
        for (int r = 0; r < 4; ++r) {
            int m = wm * 64 + i * 16 + 4 * q + r;
            int s = sidx[m];
            if (s >= 0) {
                ushort4 km4 = *(const ushort4*)&Km[(size_t)s * DD + 4 * c + 64 * wn];
                part += fmaxf(acc[i][0][r] + bv[0], 0.f) * bf2f(km4.x)
                      + fmaxf(acc[i][1][r] + bv[1], 0.f) * bf2f(km4.y)
                      + fmaxf(acc[i][2][r] + bv[2], 0.f) * bf2f(km4.z)
                      + fmaxf(acc[i][3][r] + bv[3], 0.f) * bf2f(km4.w);
            }
        }

    #pragma unroll
    for (int off = 32; off > 0; off >>= 1)
        part += __shfl_down(part, off);
    if (lane == 0) red[w] = part;
    __syncthreads();
    if (t == 0)
        atomicAdd(out, red[0] + red[1] + red[2] + red[3]);
}

// ---------------------------------------------------------------------------
extern "C" void kernel_launch(void* const* d_in, const int* in_sizes, int n_in,
                              void* d_out, int out_size, void* d_ws, size_t ws_size,
                              hipStream_t stream)
{
    const float* x     = (const float*)d_in[0];
    const int*   src   = (const int*)  d_in[1];
    const int*   dst   = (const int*)  d_in[2];
    const float* WencK = (const float*)d_in[3];
    const float* bencK = (const float*)d_in[4];
    const float* WencP1= (const float*)d_in[5];
    const float* bencP1= (const float*)d_in[6];
    const float* WencP2= (const float*)d_in[7];
    const float* bencP2= (const float*)d_in[8];
    const float* K0W   = (const float*)d_in[9];
    const float* K0b   = (const float*)d_in[10];
    const float* K1W   = (const float*)d_in[11];
    const float* K1b   = (const float*)d_in[12];
    const float* K2W   = (const float*)d_in[13];
    const float* K2b   = (const float*)d_in[14];
    const float* U0W   = (const float*)d_in[15];
    const float* U0b   = (const float*)d_in[16];
    const float* U1W   = (const float*)d_in[17];
    const float* U1b   = (const float*)d_in[18];
    const float* U2W   = (const float*)d_in[19];
    const float* U2b   = (const float*)d_in[20];

    char* ws = (char*)d_ws;
    unsigned short* wfrag = (unsigned short*)ws;             // 7*16384 bf16 = 229 KB
    float* comp  = (float*)(ws + 0x40000);                   // 3*16384 f32 = 192 KB
    float* bvecs = (float*)(ws + 0x70000);                   // 384 f32
    unsigned short* xbf  = (unsigned short*)(ws + 0x71000);  // [N,D] bf16 12.8 MB
    unsigned short* q1   = xbf + (size_t)NN * DD;
    unsigned short* q2   = q1 + (size_t)NN * DD;
    unsigned short* Kmg  = q2 + (size_t)NN * DD;
    unsigned short* xagg = Kmg + (size_t)NN * DD;
    float* kb       = (float*)(xagg + (size_t)NN * DD);
    int* cnt        = (int*)(kb + NN);
    int* base       = cnt + NN;
    int* cursor     = base + NN;
    int* sorted_src = cursor + NN;

    hipMemsetAsync(cnt, 0, NN * sizeof(int), stream);
    hipMemsetAsync(cursor, 0, NN * sizeof(int), stream);
    hipMemsetAsync(d_out, 0, sizeof(float), stream);

    composite_kernel<<<7, 256, 0, stream>>>(
        U0W, WencP1, WencP2, K0W, WencK, bencP1, bencP2, U0b, bencK, U2b,
        comp, bvecs);

    preconv_kernel<<<(7 * 2048 + 255) / 256, 256, 0, stream>>>(
        comp, K1W, K2W, U2W, U1W, wfrag);

    hist_kernel<<<(NE + 255) / 256, 256, 0, stream>>>(dst, cnt);
    scan_kernel<<<1, 1024, 0, stream>>>(cnt, base);
    place_kernel<<<(NE + 255) / 256, 256, 0, stream>>>(src, dst, base, cursor, sorted_src);

    enc_kernel<<<(NN + 127) / 128, 256, 0, stream>>>(
        x, wfrag, bvecs, q1, q2, xbf);

    agg_kernel<<<(NN + 3) / 4, 256, 0, stream>>>(xbf, base, cnt, sorted_src, xagg);

    node_kernel<<<(NN + 127) / 128, 256, 0, stream>>>(
        xagg, wfrag, cnt, bvecs, K0b, K1b, K2b, Kmg, kb);

    edge_kernel<<<(NE + 127) / 128, 256, 0, stream>>>(
        q1, q2, Kmg, kb, src, dst, wfrag, U1b, (float*)d_out);
}